// Round 1
// baseline (244.561 us; speedup 1.0000x reference)
//
#include <hip/hip_runtime.h>
#include <hip/hip_bf16.h>
#include <hip/hip_fp16.h>

typedef _Float16 f16x8 __attribute__((ext_vector_type(8)));
typedef float f32x4 __attribute__((ext_vector_type(4)));

#define S_LEN 1024
#define DH 64
#define KVB 64
#define NIT (S_LEN / KVB)
#define PAD 8
#define ROWE (64 + PAD)   // padded LDS row (elements)

__device__ __forceinline__ unsigned rotl(unsigned x, unsigned r) {
  return (x << r) | (x >> (32u - r));
}

// JAX threefry2x32, key = (0, 42), counts = (0, e)  [partitionable mode:
// 64-bit linear index split hi/lo; 32-bit draw = x0 ^ x1].
// keep = uniform([0,1)) < 0.5  <=>  top bit of (x0^x1) == 0.
__device__ __forceinline__ bool keep_bit(unsigned e) {
  const unsigned ks1 = 42u;
  const unsigned ks2 = 0x1BD11BF0u;  // 0 ^ 42 ^ 0x1BD11BDA
  unsigned x0 = 0u;        // hi32 + ks[0](=0)
  unsigned x1 = e + ks1;   // lo32 + ks[1]
#define TFR(Ra,Rb,Rc,Rd) \
  x0 += x1; x1 = rotl(x1, Ra); x1 ^= x0; \
  x0 += x1; x1 = rotl(x1, Rb); x1 ^= x0; \
  x0 += x1; x1 = rotl(x1, Rc); x1 ^= x0; \
  x0 += x1; x1 = rotl(x1, Rd); x1 ^= x0;
  TFR(13u,15u,26u, 6u)  x0 += ks1; x1 += ks2 + 1u;
  TFR(17u,29u,16u,24u)  x0 += ks2; x1 += 2u;
  TFR(13u,15u,26u, 6u)  /* x0 += 0 */ x1 += ks1 + 3u;
  TFR(17u,29u,16u,24u)  x0 += ks1; x1 += ks2 + 4u;
  TFR(13u,15u,26u, 6u)  x0 += ks2; x1 += 5u;
#undef TFR
  return ((x0 ^ x1) >> 31) == 0u;
}

__global__ __launch_bounds__(256)
void attn_dropout_kernel(const float* __restrict__ Q, const float* __restrict__ K,
                         const float* __restrict__ V, float* __restrict__ out) {
  // One block: one (b,h) head, 64 q-rows. 4 waves x 16 q-rows each.
  __shared__ _Float16 Kl[KVB][ROWE];      // [k_in_tile][d]   (fp16, padded)
  __shared__ _Float16 Vt[DH][ROWE];       // [d][k_in_tile]   (transposed)
  __shared__ _Float16 Pl[4][16][ROWE];    // per-wave P tile  [q][k_in_tile]

  const unsigned bh   = blockIdx.x >> 4;          // 0..63  (b*16+h)
  const unsigned q0   = (blockIdx.x & 15u) * 64u; // q-tile base
  const unsigned tid  = threadIdx.x;
  const unsigned w    = tid >> 6;
  const unsigned lane = tid & 63u;
  const unsigned g    = lane >> 4;     // 0..3
  const unsigned ln   = lane & 15u;    // 0..15
  const unsigned qw   = q0 + w * 16u;  // wave's q base

  // ---- hoist Q fragments (A-frag: row = ln, k(d) = g*8+j) ----
  f16x8 Qa0, Qa1;
  {
    const float* Qp = Q + (size_t)(bh * S_LEN + qw + ln) * DH + g * 8;
    f32x4 a = *(const f32x4*)(Qp);
    f32x4 b = *(const f32x4*)(Qp + 4);
    f32x4 c = *(const f32x4*)(Qp + 32);
    f32x4 d = *(const f32x4*)(Qp + 36);
#pragma unroll
    for (int i = 0; i < 4; ++i) {
      Qa0[i] = (_Float16)a[i]; Qa0[4 + i] = (_Float16)b[i];
      Qa1[i] = (_Float16)c[i]; Qa1[4 + i] = (_Float16)d[i];
    }
  }

  float mrun[4], lrun[4];
  f32x4 accO[4];
#pragma unroll
  for (int r = 0; r < 4; ++r) { mrun[r] = -1e30f; lrun[r] = 0.0f; }
#pragma unroll
  for (int n = 0; n < 4; ++n) accO[n] = (f32x4){0.f, 0.f, 0.f, 0.f};

  const unsigned kk = tid >> 2;   // 0..63  staging row
  const unsigned dg = tid & 3u;   // 0..3   staging col group (16 floats)

  for (int t = 0; t < NIT; ++t) {
    __syncthreads();   // previous tile fully consumed before overwrite
    // ---- stage K tile (fp32 -> fp16), row-major [k][d] ----
    {
      const float* Kp = K + (size_t)(bh * S_LEN + t * KVB + kk) * DH + dg * 16;
      f32x4 k0 = *(const f32x4*)(Kp);
      f32x4 k1 = *(const f32x4*)(Kp + 4);
      f32x4 k2 = *(const f32x4*)(Kp + 8);
      f32x4 k3 = *(const f32x4*)(Kp + 12);
      f16x8 w0, w1;
#pragma unroll
      for (int i = 0; i < 4; ++i) {
        w0[i] = (_Float16)k0[i]; w0[4 + i] = (_Float16)k1[i];
        w1[i] = (_Float16)k2[i]; w1[4 + i] = (_Float16)k3[i];
      }
      *(f16x8*)&Kl[kk][dg * 16]     = w0;
      *(f16x8*)&Kl[kk][dg * 16 + 8] = w1;
    }
    // ---- stage V tile transposed [d][k] ----
    {
      const float* Vp = V + (size_t)(bh * S_LEN + t * KVB + kk) * DH + dg * 16;
      f32x4 v0 = *(const f32x4*)(Vp);
      f32x4 v1 = *(const f32x4*)(Vp + 4);
      f32x4 v2 = *(const f32x4*)(Vp + 8);
      f32x4 v3 = *(const f32x4*)(Vp + 12);
#pragma unroll
      for (int i = 0; i < 4; ++i) {
        Vt[dg * 16 +  0 + i][kk] = (_Float16)v0[i];
        Vt[dg * 16 +  4 + i][kk] = (_Float16)v1[i];
        Vt[dg * 16 +  8 + i][kk] = (_Float16)v2[i];
        Vt[dg * 16 + 12 + i][kk] = (_Float16)v3[i];
      }
    }
    __syncthreads();

    // ---- S = Q K^T for this wave's 16 q-rows x 64 k-cols ----
    f32x4 sc[4];
#pragma unroll
    for (int nt = 0; nt < 4; ++nt) {
      f16x8 kb0 = *(const f16x8*)&Kl[nt * 16 + ln][g * 8];
      f16x8 kb1 = *(const f16x8*)&Kl[nt * 16 + ln][32 + g * 8];
      f32x4 a = (f32x4){0.f, 0.f, 0.f, 0.f};
      a = __builtin_amdgcn_mfma_f32_16x16x32_f16(Qa0, kb0, a, 0, 0, 0);
      a = __builtin_amdgcn_mfma_f32_16x16x32_f16(Qa1, kb1, a, 0, 0, 0);
      sc[nt] = a;
    }

    // ---- dropout mask (threefry) + masked scores ----
    // D-layout: q = qw + g*4 + r, kcol = t*64 + nt*16 + ln
    float sm[4][4];
#pragma unroll
    for (int nt = 0; nt < 4; ++nt) {
#pragma unroll
      for (int r = 0; r < 4; ++r) {
        unsigned q  = qw + g * 4 + r;
        unsigned kg = (unsigned)t * KVB + nt * 16 + ln;
        unsigned e  = (bh << 20) + (q << 10) + kg;  // ((b*16+h)*1024+q)*1024+k
        float s2 = sc[nt][r] * 2.0f;                // score / (1-p)
        sm[nt][r] = keep_bit(e) ? s2 : 0.0f;        // dropped -> 0 (NOT -inf)
      }
    }

    // ---- online softmax update ----
    float ps[4][4];
#pragma unroll
    for (int r = 0; r < 4; ++r) {
      float mx = fmaxf(fmaxf(sm[0][r], sm[1][r]), fmaxf(sm[2][r], sm[3][r]));
#pragma unroll
      for (int off = 1; off < 16; off <<= 1) mx = fmaxf(mx, __shfl_xor(mx, off));
      float mn = fmaxf(mrun[r], mx);
      float scl = __expf(mrun[r] - mn);
      mrun[r] = mn;
      float rs = 0.f;
#pragma unroll
      for (int nt = 0; nt < 4; ++nt) {
        float p = __expf(sm[nt][r] - mn);
        ps[nt][r] = p; rs += p;
      }
#pragma unroll
      for (int off = 1; off < 16; off <<= 1) rs += __shfl_xor(rs, off);
      lrun[r] = lrun[r] * scl + rs;
#pragma unroll
      for (int n = 0; n < 4; ++n) accO[n][r] *= scl;
    }

    // ---- P -> wave-private LDS (re-layout for PV A-frag) ----
#pragma unroll
    for (int nt = 0; nt < 4; ++nt)
#pragma unroll
      for (int r = 0; r < 4; ++r)
        Pl[w][g * 4 + r][nt * 16 + ln] = (_Float16)ps[nt][r];

    // ---- O += P V ----
    f16x8 Pa0 = *(const f16x8*)&Pl[w][ln][g * 8];
    f16x8 Pa1 = *(const f16x8*)&Pl[w][ln][32 + g * 8];
#pragma unroll
    for (int nd = 0; nd < 4; ++nd) {
      f16x8 vb0 = *(const f16x8*)&Vt[nd * 16 + ln][g * 8];
      f16x8 vb1 = *(const f16x8*)&Vt[nd * 16 + ln][32 + g * 8];
      accO[nd] = __builtin_amdgcn_mfma_f32_16x16x32_f16(Pa0, vb0, accO[nd], 0, 0, 0);
      accO[nd] = __builtin_amdgcn_mfma_f32_16x16x32_f16(Pa1, vb1, accO[nd], 0, 0, 0);
    }
  }

  // ---- epilogue: O / l ----
#pragma unroll
  for (int nd = 0; nd < 4; ++nd) {
#pragma unroll
    for (int r = 0; r < 4; ++r) {
      unsigned q = qw + g * 4 + r;
      out[(size_t)(bh * S_LEN + q) * DH + nd * 16 + ln] = accO[nd][r] / lrun[r];
    }
  }
}

extern "C" void kernel_launch(void* const* d_in, const int* in_sizes, int n_in,
                              void* d_out, int out_size, void* d_ws, size_t ws_size,
                              hipStream_t stream) {
  const float* Q = (const float*)d_in[0];
  const float* K = (const float*)d_in[1];
  const float* V = (const float*)d_in[2];
  float* out = (float*)d_out;
  dim3 grid(64 * 16);   // (b*16+h) * 16 q-tiles
  dim3 block(256);
  hipLaunchKernelGGL(attn_dropout_kernel, grid, block, 0, stream, Q, K, V, out);
}